// Round 14
// baseline (325.366 us; speedup 1.0000x reference)
//
#include <hip/hip_runtime.h>
#include <hip/hip_bf16.h>
#include <cstdint>
#include <cstddef>

typedef __bf16 bf16_t;
typedef __attribute__((ext_vector_type(8))) __bf16 bf16x8;
typedef __attribute__((ext_vector_type(4))) __bf16 bf16x4;
typedef __attribute__((ext_vector_type(4))) float f32x4;

#define B_ 2
#define T_ 2048
#define DIM_ 2048
#define H_ 16
#define DH_ 128
#define DD_ 64
#define DQK_ 192              // DH_ + DD_
#define QSTRIDE_ 3072         // H_ * DQK_
#define BT_ 4096              // B_ * T_
#define SCALE_ 0.07216878364870322f   // 1/sqrt(192), pre-applied to Q

__device__ __forceinline__ void gload16(const void* g, void* lds) {
  __builtin_amdgcn_global_load_lds(
      (const __attribute__((address_space(1))) unsigned int*)g,
      (__attribute__((address_space(3))) unsigned int*)lds, 16, 0, 0);
}

// ---------------- cast x (fp32 -> bf16, vectorized) ----------------
struct bf16_4 { bf16_t a, b, c, d; };
__global__ void cast_f32_bf16(const float* __restrict__ in, bf16_t* __restrict__ out, int n4) {
  int i = blockIdx.x * blockDim.x + threadIdx.x;
  if (i >= n4) return;
  float4 v = ((const float4*)in)[i];
  bf16_4 r{(bf16_t)v.x, (bf16_t)v.y, (bf16_t)v.z, (bf16_t)v.w};
  ((bf16_4*)out)[i] = r;
}

// ------------- ALL weight transposes in ONE launch -------------
__global__ void transpose_all(const float* __restrict__ Wdq, const float* __restrict__ Wdkv,
                              const float* __restrict__ Wkr, const float* __restrict__ Wuq,
                              const float* __restrict__ Wqr, const float* __restrict__ Wuk,
                              const float* __restrict__ Wuv, const float* __restrict__ Wo,
                              bf16_t* __restrict__ Bt1, bf16_t* __restrict__ Bt2,
                              bf16_t* __restrict__ Bt3, bf16_t* __restrict__ Wo_t) {
  __shared__ float tile[32][33];
  int id = blockIdx.x;
  const float* W; bf16_t* Wt; int K, N, Np, kt;
  if (id < 1024)      { W = Wdq;  Wt = Bt1;                          K = 2048; N = 512;  Np = 512;  kt = 64; }
  else if (id < 2048) { W = Wdkv; Wt = Bt1 + (size_t)512 * 2048;  id -= 1024; K = 2048; N = 512;  Np = 512;  kt = 64; }
  else if (id < 2304) { W = Wkr;  Wt = Bt1 + (size_t)1024 * 2048; id -= 2048; K = 2048; N = 64;   Np = 128;  kt = 64; }
  else if (id < 3328) { W = Wuq;  Wt = Bt2;                       id -= 2304; K = 512;  N = 2048; Np = 2048; kt = 16; }
  else if (id < 3840) { W = Wqr;  Wt = Bt2 + (size_t)2048 * 512;  id -= 3328; K = 512;  N = 1024; Np = 1024; kt = 16; }
  else if (id < 4864) { W = Wuk;  Wt = Bt3;                       id -= 3840; K = 512;  N = 2048; Np = 2048; kt = 16; }
  else if (id < 5888) { W = Wuv;  Wt = Bt3 + (size_t)2048 * 512;  id -= 4864; K = 512;  N = 2048; Np = 2048; kt = 16; }
  else                { W = Wo;   Wt = Wo_t;                      id -= 5888; K = 2048; N = 2048; Np = 2048; kt = 64; }
  int k0 = (id % kt) * 32, n0 = (id / kt) * 32;
  int tx = threadIdx.x, ty = threadIdx.y;
#pragma unroll
  for (int i = 0; i < 4; ++i) {
    int k = k0 + ty + i * 8, n = n0 + tx;
    float v = (k < K && n < N) ? W[(size_t)k * N + n] : 0.f;
    tile[ty + i * 8][tx] = v;
  }
  __syncthreads();
#pragma unroll
  for (int i = 0; i < 4; ++i) {
    int n = n0 + ty + i * 8, k = k0 + tx;
    if (n < Np && k < K) Wt[(size_t)n * K + k] = (bf16_t)tile[tx][ty + i * 8];
  }
}

// ------------- transpose V: Vbuf[BT][2048] -> Vt[bh=32][128][T] -------------
__global__ void transpose_v(const bf16_t* __restrict__ V, bf16_t* __restrict__ Vt) {
  __shared__ bf16_t tile[64 * 64];
  int id = blockIdx.x;
  int t0 = (id & 31) * 64;
  int d0 = ((id >> 5) & 1) * 64;
  int bh = id >> 6;  // 0..31
  int b = bh >> 4, h = bh & 15;
  int t = threadIdx.x;
#pragma unroll
  for (int it = 0; it < 2; ++it) {
    int idx = it * 256 + t;
    int tt = idx >> 3, c = idx & 7;
    bf16x8 v = *(const bf16x8*)&V[(size_t)(b * T_ + t0 + tt) * 2048 + h * 128 + d0 + c * 8];
    int sw = (tt ^ (tt >> 3)) & 7;
    *(bf16x8*)((char*)tile + tt * 128 + 16 * (c ^ sw)) = v;
  }
  __syncthreads();
#pragma unroll
  for (int it = 0; it < 2; ++it) {
    int idx = it * 256 + t;
    int dr = idx >> 3, c = idx & 7;
    bf16_t tmp[8];
#pragma unroll
    for (int u = 0; u < 8; ++u) {
      int sw = (u ^ c) & 7;
      tmp[u] = *(const bf16_t*)((const char*)tile + (8 * c + u) * 128 + ((2 * dr) ^ (16 * sw)));
    }
    *(bf16x8*)&Vt[((size_t)bh * 128 + d0 + dr) * T_ + t0 + c * 8] = *(bf16x8*)tmp;
  }
}

// ---------------- GEMM (BK=64, source-swizzled gload_lds; R13-proven) ----------------
// MODE 1: fp32 out.  MODE 3: q_c | kv_c | rope-k rotate+broadcast into Kbuf.
// MODE 4: Qbuf head-interleaved PRE-SCALED | in-reg RoPE-q (scaled).  MODE 5: Kbuf | Vbuf.
template <int MODE>
__global__ __launch_bounds__(256) void gemm_bt(const bf16_t* __restrict__ A,
                                               const bf16_t* __restrict__ Bt,
                                               void* __restrict__ C0v,
                                               void* __restrict__ C1v,
                                               void* __restrict__ C2v,
                                               const float* __restrict__ fr,
                                               int M, int N, int K, int ldc) {
  __shared__ bf16_t As[128 * 64];
  __shared__ bf16_t Bs[128 * 64];
  const int t = threadIdx.x;
  const int w = t >> 6, l = t & 63, l15 = l & 15, lhi = l >> 4;
  const int m0 = blockIdx.y * 128, n0 = blockIdx.x * 128;
  const int wr = (w >> 1) * 64, wc = (w & 1) * 64;

  f32x4 zero = {0.f, 0.f, 0.f, 0.f};
  f32x4 acc[4][4];
#pragma unroll
  for (int m = 0; m < 4; ++m)
#pragma unroll
    for (int n = 0; n < 4; ++n) acc[m][n] = zero;

  const int srow = t >> 3;
  const int scol = (((t & 7) ^ (srow & 7)) << 3);
  const int ldst = t * 8;

  for (int k0 = 0; k0 < K; k0 += 64) {
#pragma unroll
    for (int j = 0; j < 4; ++j) {
      gload16(A + (size_t)(m0 + srow + j * 32) * K + k0 + scol, &As[ldst + j * 2048]);
      gload16(Bt + (size_t)(n0 + srow + j * 32) * K + k0 + scol, &Bs[ldst + j * 2048]);
    }
    __syncthreads();
#pragma unroll
    for (int kk = 0; kk < 2; ++kk) {
      const int xs = ((((kk << 2) + lhi) ^ (l15 & 7)) << 3);
      bf16x8 af[4], bfr[4];
#pragma unroll
      for (int m = 0; m < 4; ++m)
        af[m] = *(const bf16x8*)&As[(wr + m * 16 + l15) * 64 + xs];
#pragma unroll
      for (int n = 0; n < 4; ++n)
        bfr[n] = *(const bf16x8*)&Bs[(wc + n * 16 + l15) * 64 + xs];
#pragma unroll
      for (int m = 0; m < 4; ++m)
#pragma unroll
        for (int n = 0; n < 4; ++n)
          acc[m][n] = __builtin_amdgcn_mfma_f32_16x16x32_bf16(af[m], bfr[n], acc[m][n], 0, 0, 0);
    }
    __syncthreads();
  }

#pragma unroll
  for (int m = 0; m < 4; ++m) {
#pragma unroll
    for (int n = 0; n < 4; ++n) {
#pragma unroll
      for (int r = 0; r < 4; ++r) {
        int row = m0 + wr + m * 16 + lhi * 4 + r;
        int col = n0 + wc + n * 16 + l15;
        float v = acc[m][n][r];
        if (MODE == 1) {
          ((float*)C0v)[(size_t)row * ldc + col] = v;
        } else if (MODE == 3) {
          if (col < 512) {
            ((bf16_t*)C0v)[(size_t)row * 512 + col] = (bf16_t)v;
          } else if (col < 1024) {
            ((bf16_t*)C1v)[(size_t)row * 512 + (col - 512)] = (bf16_t)v;
          } else if (col < 1088) {
            float other = __shfl_xor(v, 1, 64);
            int tt = row & (T_ - 1);
            int j = (col - 1024) >> 1;
            float2 cs = ((const float2*)fr)[tt * 32 + j];
            float o = (col & 1) ? (other * cs.y + v * cs.x) : (v * cs.x - other * cs.y);
            float o2 = __shfl_xor(o, 1, 64);
            if (!(col & 1)) {
              union { bf16_t h2[2]; unsigned u; } pk;
              pk.h2[0] = (bf16_t)o;
              pk.h2[1] = (bf16_t)o2;
              bf16_t* Kb = (bf16_t*)C2v;
#pragma unroll
              for (int hh = 0; hh < H_; ++hh)
                *(unsigned*)&Kb[(size_t)row * QSTRIDE_ + hh * DQK_ + 128 + (col - 1024)] = pk.u;
            }
          }
        } else if (MODE == 4) {
          if (col < 2048) {
            ((bf16_t*)C0v)[(size_t)row * QSTRIDE_ + (col >> 7) * DQK_ + (col & 127)] =
                (bf16_t)(v * SCALE_);
          } else {
            float other = __shfl_xor(v, 1, 64);
            int tt = row & (T_ - 1);
            int j = (col & 63) >> 1;
            float2 cs = ((const float2*)fr)[tt * 32 + j];
            float o = (col & 1) ? (other * cs.y + v * cs.x) : (v * cs.x - other * cs.y);
            int hh = (col - 2048) >> 6;
            ((bf16_t*)C0v)[(size_t)row * QSTRIDE_ + hh * DQK_ + 128 + (col & 63)] =
                (bf16_t)(o * SCALE_);
          }
        } else if (MODE == 5) {
          if (col < 2048) ((bf16_t*)C0v)[(size_t)row * QSTRIDE_ + (col >> 7) * DQK_ + (col & 127)] = (bf16_t)v;
          else            ((bf16_t*)C1v)[(size_t)row * 2048 + (col - 2048)] = (bf16_t)v;
        }
      }
    }
  }
}

// ---------------- causal flash attention v7 ----------------
// 512 blocks x 256 threads, 128-row q-tile per block, 4 waves x 32 rows
// (2 fragment sets per wave -> every kf/vf LDS read feeds 2 MFMAs: reads per
// q-row HALVED vs v3). Cost-complementary ID layout keeps both likely CU
// co-residency patterns ({2c,2c+1} and {c,c+256}) at exactly 34 steps.
// v3 shell otherwise: reg-staged single-buffered K/V, defer-max, deferred
// l-reduce, pre-scaled Q. LDS 61440 B -> 2 blocks/CU.
#define KLDB 200
#define VLDB 72
#define PLDB 68

__global__ __launch_bounds__(256, 2) void flash_attn7(const bf16_t* __restrict__ Q,
                                                      const bf16_t* __restrict__ Kb,
                                                      const bf16_t* __restrict__ Vt,
                                                      bf16_t* __restrict__ Ob) {
  __shared__ bf16_t Ks[64 * KLDB];      // 25600 B
  __shared__ bf16_t Vs[128 * VLDB];     // 18432 B
  __shared__ bf16_t Ps[4][32 * PLDB];   // 17408 B  (total 61440)

  const int t = threadIdx.x, w = t >> 6, l = t & 63, l15 = l & 15, lhi = l >> 4;
  // ID decode: both {2c,2c+1} and {c,c+256} pairings sum to 34 steps.
  const int id = blockIdx.x;
  const int uu = id >> 1, pp = id & 1;
  const int bh = (pp << 4) | (uu >> 4);
  const int g = (uu & 15) ^ ((uu >> 7) ? 15 : 0);
  const int qt = pp ? (15 - g) : g;          // 128-row tile index, 0..15
  const int b = bh >> 4, h = bh & 15;
  const int nkt = 2 * qt + 2;                // k-tiles of 64
  const int myLast = 2 * qt + (w >= 2 ? 1 : 0);
  const int qoff = (w >= 2) ? 64 : 0;        // diag-mask row offset

  // staging thread->slot maps (v3)
  int rK[6], cK[6];
#pragma unroll
  for (int i = 0; i < 6; ++i) { int idx = i * 256 + t; rK[i] = idx / 24; cK[i] = idx % 24; }
  const int rVt = t >> 3, cV = t & 7;
  const bf16_t* kbase = Kb + (size_t)b * T_ * QSTRIDE_ + h * DQK_;
  const bf16_t* vbase = Vt + (size_t)bh * DH_ * T_;

  bf16x8 kreg[6], vreg[4];
#define LOAD_TILE(K0)                                                                      \
  do {                                                                                     \
    _Pragma("unroll") for (int i = 0; i < 6; ++i)                                          \
        kreg[i] = *(const bf16x8*)(kbase + (size_t)((K0) + rK[i]) * QSTRIDE_ + cK[i] * 8); \
    _Pragma("unroll") for (int i = 0; i < 4; ++i)                                          \
        vreg[i] = *(const bf16x8*)(vbase + (size_t)(i * 32 + rVt) * T_ + (K0) + cV * 8);   \
  } while (0)
#define WRITE_TILE()                                                                       \
  do {                                                                                     \
    _Pragma("unroll") for (int i = 0; i < 6; ++i)                                          \
        *(bf16x8*)&Ks[rK[i] * KLDB + cK[i] * 8] = kreg[i];                                 \
    _Pragma("unroll") for (int i = 0; i < 4; ++i)                                          \
        *(bf16x8*)&Vs[(i * 32 + rVt) * VLDB + cV * 8] = vreg[i];                           \
  } while (0)

  f32x4 zero = {0.f, 0.f, 0.f, 0.f};

  // Q fragments: 2 sets of 16 rows (wave owns rows w*32 .. w*32+31 of the tile)
  bf16x8 qf[2][6];
#pragma unroll
  for (int u = 0; u < 2; ++u) {
    const bf16_t* qrow =
        Q + ((size_t)(b * T_ + qt * 128 + w * 32 + u * 16 + l15)) * QSTRIDE_ + h * DQK_;
#pragma unroll
    for (int kc = 0; kc < 6; ++kc) qf[u][kc] = *(const bf16x8*)(qrow + kc * 32 + lhi * 8);
  }

  float m_r[2][4], l_r[2][4];
  f32x4 accO[2][8];
#pragma unroll
  for (int u = 0; u < 2; ++u) {
#pragma unroll
    for (int r = 0; r < 4; ++r) { m_r[u][r] = -1e30f; l_r[u][r] = 0.f; }
#pragma unroll
    for (int n = 0; n < 8; ++n) accO[u][n] = zero;
  }

  LOAD_TILE(0);
  WRITE_TILE();
  __syncthreads();

  for (int kt = 0; kt < nkt; ++kt) {
    const bool lastStep = (kt == nkt - 1);
    if (!lastStep) LOAD_TILE((kt + 1) * 64);  // prefetch into regs

    if (kt <= myLast) {
      const bool diag = (kt == myLast);

      // QK^T: each kf read feeds both fragment sets
      f32x4 s[2][4];
#pragma unroll
      for (int u = 0; u < 2; ++u)
#pragma unroll
        for (int n = 0; n < 4; ++n) s[u][n] = zero;
      __builtin_amdgcn_s_setprio(1);
#pragma unroll
      for (int kc = 0; kc < 6; ++kc) {
#pragma unroll
        for (int n = 0; n < 4; ++n) {
          bf16x8 kf = *(const bf16x8*)&Ks[(n * 16 + l15) * KLDB + kc * 32 + lhi * 8];
          s[0][n] = __builtin_amdgcn_mfma_f32_16x16x32_bf16(qf[0][kc], kf, s[0][n], 0, 0, 0);
          s[1][n] = __builtin_amdgcn_mfma_f32_16x16x32_bf16(qf[1][kc], kf, s[1][n], 0, 0, 0);
        }
      }
      __builtin_amdgcn_s_setprio(0);

      // mask on diagonal k-tile (Q pre-scaled)
      if (diag) {
#pragma unroll
        for (int u = 0; u < 2; ++u)
#pragma unroll
          for (int n = 0; n < 4; ++n)
#pragma unroll
            for (int r = 0; r < 4; ++r) {
              int qq = w * 32 + u * 16 + lhi * 4 + r - qoff;  // 0..63 within k-tile
              int kk = n * 16 + l15;
              if (kk > qq) s[u][n][r] = -1e30f;
            }
      }
      // per-tile row max
      float pmax[2][4];
#pragma unroll
      for (int u = 0; u < 2; ++u)
#pragma unroll
        for (int r = 0; r < 4; ++r) {
          float v = fmaxf(fmaxf(s[u][0][r], s[u][1][r]), fmaxf(s[u][2][r], s[u][3][r]));
#pragma unroll
          for (int off = 1; off < 16; off <<= 1) v = fmaxf(v, __shfl_xor(v, off, 64));
          pmax[u][r] = v;
        }
      // T13 defer-max across both sets
      bool need = false;
#pragma unroll
      for (int u = 0; u < 2; ++u)
#pragma unroll
        for (int r = 0; r < 4; ++r) need = need || (pmax[u][r] > m_r[u][r] + 8.0f);
      if (__any(need ? 1 : 0)) {
#pragma unroll
        for (int u = 0; u < 2; ++u) {
          float corr[4];
#pragma unroll
          for (int r = 0; r < 4; ++r) {
            float mn = fmaxf(m_r[u][r], pmax[u][r]);
            corr[r] = __expf(m_r[u][r] - mn);
            m_r[u][r] = mn;
            l_r[u][r] *= corr[r];
          }
#pragma unroll
          for (int n = 0; n < 8; ++n)
#pragma unroll
            for (int r = 0; r < 4; ++r) accO[u][n][r] *= corr[r];
        }
      }
#pragma unroll
      for (int u = 0; u < 2; ++u)
#pragma unroll
        for (int n = 0; n < 4; ++n)
#pragma unroll
          for (int r = 0; r < 4; ++r) {
            float p = __expf(s[u][n][r] - m_r[u][r]);
            l_r[u][r] += p;  // per-lane partial; reduced once in epilogue
            Ps[w][(u * 16 + lhi * 4 + r) * PLDB + n * 16 + l15] = (bf16_t)p;
          }

      // PV: each vf read feeds both fragment sets
      __builtin_amdgcn_s_setprio(1);
#pragma unroll
      for (int kc = 0; kc < 2; ++kc) {
        bf16x8 pf[2];
#pragma unroll
        for (int u = 0; u < 2; ++u) {
          const bf16_t* pb = &Ps[w][(u * 16 + l15) * PLDB + kc * 32 + lhi * 8];
          bf16x4 p0 = *(const bf16x4*)pb;
          bf16x4 p1 = *(const bf16x4*)(pb + 4);
          pf[u] = __builtin_shufflevector(p0, p1, 0, 1, 2, 3, 4, 5, 6, 7);
        }
#pragma unroll
        for (int n = 0; n < 8; ++n) {
          bf16x8 vf = *(const bf16x8*)&Vs[(n * 16 + l15) * VLDB + kc * 32 + lhi * 8];
          accO[0][n] = __builtin_amdgcn_mfma_f32_16x16x32_bf16(pf[0], vf, accO[0][n], 0, 0, 0);
          accO[1][n] = __builtin_amdgcn_mfma_f32_16x16x32_bf16(pf[1], vf, accO[1][n], 0, 0, 0);
        }
      }
      __builtin_amdgcn_s_setprio(0);
    }

    __syncthreads();            // all LDS reads of tile kt done
    if (!lastStep) {
      WRITE_TILE();             // publish next tile
      __syncthreads();
    }
  }

  // store O: 32 rows per wave (l-reduce once)
#pragma unroll
  for (int u = 0; u < 2; ++u) {
    float inv[4];
#pragma unroll
    for (int r = 0; r < 4; ++r) {
      float v = l_r[u][r];
#pragma unroll
      for (int off = 1; off < 16; off <<= 1) v += __shfl_xor(v, off, 64);
      inv[r] = 1.0f / v;
    }
#pragma unroll
    for (int n = 0; n < 8; ++n)
#pragma unroll
      for (int r = 0; r < 4; ++r) {
        size_t row = (size_t)(b * T_ + qt * 128 + w * 32 + u * 16 + lhi * 4 + r);
        Ob[row * (H_ * DH_) + h * DH_ + n * 16 + l15] = (bf16_t)(accO[u][n][r] * inv[r]);
      }
  }
#undef LOAD_TILE
#undef WRITE_TILE
}

// ---------------- host ----------------
extern "C" void kernel_launch(void* const* d_in, const int* in_sizes, int n_in,
                              void* d_out, int out_size, void* d_ws, size_t ws_size,
                              hipStream_t stream) {
  (void)in_sizes; (void)n_in; (void)out_size; (void)ws_size;
  const float* x    = (const float*)d_in[0];
  const float* fr   = (const float*)d_in[1];
  // d_in[2] = mask (unused; causal handled analytically)
  const float* Wdq  = (const float*)d_in[3];
  const float* Wuq  = (const float*)d_in[4];
  const float* Wdkv = (const float*)d_in[5];
  const float* Wuk  = (const float*)d_in[6];
  const float* Wuv  = (const float*)d_in[7];
  const float* Wqr  = (const float*)d_in[8];
  const float* Wkr  = (const float*)d_in[9];
  const float* Wo   = (const float*)d_in[10];
  float* out = (float*)d_out;

  char* ws = (char*)d_ws;
  size_t off = 0;
  auto alloc = [&](size_t bytes) -> void* {
    void* p = ws + off;
    off += (bytes + 255) & ~(size_t)255;
    return p;
  };
  bf16_t* x_bf   = (bf16_t*)alloc((size_t)BT_ * DIM_ * 2);
  bf16_t* Bt1    = (bf16_t*)alloc((size_t)1152 * 2048 * 2);  // [Wdq(512) | Wdkv(512) | Wkr(128 pad)]
  bf16_t* Bt2    = (bf16_t*)alloc((size_t)3072 * 512 * 2);   // [Wuq(2048) | Wqr(1024)]
  bf16_t* Bt3    = (bf16_t*)alloc((size_t)4096 * 512 * 2);   // [Wuk(2048) | Wuv(2048)]
  bf16_t* Wo_t   = (bf16_t*)alloc((size_t)2048 * 2048 * 2);
  bf16_t* q_c    = (bf16_t*)alloc((size_t)BT_ * 512 * 2);
  bf16_t* kv_c   = (bf16_t*)alloc((size_t)BT_ * 512 * 2);
  bf16_t* Qbuf   = (bf16_t*)alloc((size_t)BT_ * QSTRIDE_ * 2);
  bf16_t* Kbuf   = (bf16_t*)alloc((size_t)BT_ * QSTRIDE_ * 2);
  bf16_t* Vbuf   = (bf16_t*)alloc((size_t)BT_ * 2048 * 2);
  bf16_t* Vt_g   = (bf16_t*)alloc((size_t)BT_ * 2048 * 2);
  bf16_t* AObuf  = (bf16_t*)alloc((size_t)BT_ * 2048 * 2);

  cast_f32_bf16<<<(BT_ * DIM_ / 4 + 255) / 256, 256, 0, stream>>>(x, x_bf, BT_ * DIM_ / 4);
  transpose_all<<<9984, dim3(32, 8), 0, stream>>>(Wdq, Wdkv, Wkr, Wuq, Wqr, Wuk, Wuv, Wo,
                                                  Bt1, Bt2, Bt3, Wo_t);

  // fused projections (MODE3 fuses rope-k broadcast; MODE4 fuses RoPE-q + Q pre-scale)
  gemm_bt<3><<<dim3(9, 32),  256, 0, stream>>>(x_bf, Bt1, q_c, kv_c, Kbuf, fr, BT_, 1088, 2048, 0);
  gemm_bt<4><<<dim3(24, 32), 256, 0, stream>>>(q_c,  Bt2, Qbuf, nullptr, nullptr, fr, BT_, 3072, 512, 0);
  gemm_bt<5><<<dim3(32, 32), 256, 0, stream>>>(kv_c, Bt3, Kbuf, Vbuf, nullptr, nullptr, BT_, 4096, 512, 0);

  transpose_v<<<2048, 256, 0, stream>>>(Vbuf, Vt_g);

  flash_attn7<<<512, 256, 0, stream>>>(Qbuf, Kbuf, Vt_g, AObuf);

  // output projection -> fp32
  gemm_bt<1><<<dim3(16, 32), 256, 0, stream>>>(AObuf, Wo_t, out, nullptr, nullptr, nullptr, BT_, 2048, 2048, 2048);
}

// Round 15
// 291.100 us; speedup vs baseline: 1.1177x; 1.1177x over previous
//
#include <hip/hip_runtime.h>
#include <hip/hip_bf16.h>
#include <cstdint>
#include <cstddef>

typedef __bf16 bf16_t;
typedef __attribute__((ext_vector_type(8))) __bf16 bf16x8;
typedef __attribute__((ext_vector_type(4))) __bf16 bf16x4;
typedef __attribute__((ext_vector_type(4))) float f32x4;

#define B_ 2
#define T_ 2048
#define DIM_ 2048
#define H_ 16
#define DH_ 128
#define DD_ 64
#define DQK_ 192              // DH_ + DD_
#define QSTRIDE_ 3072         // H_ * DQK_
#define BT_ 4096              // B_ * T_
#define SCALE_ 0.07216878364870322f   // 1/sqrt(192), pre-applied to Q

__device__ __forceinline__ void gload16(const void* g, void* lds) {
  __builtin_amdgcn_global_load_lds(
      (const __attribute__((address_space(1))) unsigned int*)g,
      (__attribute__((address_space(3))) unsigned int*)lds, 16, 0, 0);
}

struct bf16_4 { bf16_t a, b, c, d; };

// ------------- prep: ALL weight transposes + x cast in ONE launch (R10-proven) -------------
__global__ void prep(const float* __restrict__ x,
                     const float* __restrict__ Wdq, const float* __restrict__ Wdkv,
                     const float* __restrict__ Wkr, const float* __restrict__ Wuq,
                     const float* __restrict__ Wqr, const float* __restrict__ Wuk,
                     const float* __restrict__ Wuv, const float* __restrict__ Wo,
                     bf16_t* __restrict__ x_bf,
                     bf16_t* __restrict__ Bt1, bf16_t* __restrict__ Bt2,
                     bf16_t* __restrict__ Bt3, bf16_t* __restrict__ Wo_t) {
  int id = blockIdx.x;
  if (id >= 9984) {
    // cast x fp32 -> bf16, float4-vectorized; exactly BT_*DIM_/4 threads
    int i = (id - 9984) * 256 + threadIdx.y * 32 + threadIdx.x;
    float4 v = ((const float4*)x)[i];
    bf16_4 r{(bf16_t)v.x, (bf16_t)v.y, (bf16_t)v.z, (bf16_t)v.w};
    ((bf16_4*)x_bf)[i] = r;
    return;
  }
  __shared__ float tile[32][33];
  const float* W; bf16_t* Wt; int K, N, Np, kt;
  if (id < 1024)      { W = Wdq;  Wt = Bt1;                          K = 2048; N = 512;  Np = 512;  kt = 64; }
  else if (id < 2048) { W = Wdkv; Wt = Bt1 + (size_t)512 * 2048;  id -= 1024; K = 2048; N = 512;  Np = 512;  kt = 64; }
  else if (id < 2304) { W = Wkr;  Wt = Bt1 + (size_t)1024 * 2048; id -= 2048; K = 2048; N = 64;   Np = 128;  kt = 64; }
  else if (id < 3328) { W = Wuq;  Wt = Bt2;                       id -= 2304; K = 512;  N = 2048; Np = 2048; kt = 16; }
  else if (id < 3840) { W = Wqr;  Wt = Bt2 + (size_t)2048 * 512;  id -= 3328; K = 512;  N = 1024; Np = 1024; kt = 16; }
  else if (id < 4864) { W = Wuk;  Wt = Bt3;                       id -= 3840; K = 512;  N = 2048; Np = 2048; kt = 16; }
  else if (id < 5888) { W = Wuv;  Wt = Bt3 + (size_t)2048 * 512;  id -= 4864; K = 512;  N = 2048; Np = 2048; kt = 16; }
  else                { W = Wo;   Wt = Wo_t;                      id -= 5888; K = 2048; N = 2048; Np = 2048; kt = 64; }
  int k0 = (id % kt) * 32, n0 = (id / kt) * 32;
  int tx = threadIdx.x, ty = threadIdx.y;
#pragma unroll
  for (int i = 0; i < 4; ++i) {
    int k = k0 + ty + i * 8, n = n0 + tx;
    float v = (k < K && n < N) ? W[(size_t)k * N + n] : 0.f;
    tile[ty + i * 8][tx] = v;
  }
  __syncthreads();
#pragma unroll
  for (int i = 0; i < 4; ++i) {
    int n = n0 + ty + i * 8, k = k0 + tx;
    if (n < Np && k < K) Wt[(size_t)n * K + k] = (bf16_t)tile[tx][ty + i * 8];
  }
}

// ------------- transpose V: Vbuf[BT][2048] -> Vt[bh=32][128][T] -------------
__global__ void transpose_v(const bf16_t* __restrict__ V, bf16_t* __restrict__ Vt) {
  __shared__ bf16_t tile[64 * 64];
  int id = blockIdx.x;
  int t0 = (id & 31) * 64;
  int d0 = ((id >> 5) & 1) * 64;
  int bh = id >> 6;  // 0..31
  int b = bh >> 4, h = bh & 15;
  int t = threadIdx.x;
#pragma unroll
  for (int it = 0; it < 2; ++it) {
    int idx = it * 256 + t;
    int tt = idx >> 3, c = idx & 7;
    bf16x8 v = *(const bf16x8*)&V[(size_t)(b * T_ + t0 + tt) * 2048 + h * 128 + d0 + c * 8];
    int sw = (tt ^ (tt >> 3)) & 7;
    *(bf16x8*)((char*)tile + tt * 128 + 16 * (c ^ sw)) = v;
  }
  __syncthreads();
#pragma unroll
  for (int it = 0; it < 2; ++it) {
    int idx = it * 256 + t;
    int dr = idx >> 3, c = idx & 7;
    bf16_t tmp[8];
#pragma unroll
    for (int u = 0; u < 8; ++u) {
      int sw = (u ^ c) & 7;
      tmp[u] = *(const bf16_t*)((const char*)tile + (8 * c + u) * 128 + ((2 * dr) ^ (16 * sw)));
    }
    *(bf16x8*)&Vt[((size_t)bh * 128 + d0 + dr) * T_ + t0 + c * 8] = *(bf16x8*)tmp;
  }
}

// ---------------- GEMM (BK=64, source-swizzled gload_lds; R13-proven) ----------------
// MODE 1: fp32 out.  MODE 3: q_c | kv_c | rope-k rotate+broadcast into Kbuf.
// MODE 4: Qbuf head-interleaved PRE-SCALED | in-reg RoPE-q (scaled).  MODE 5: Kbuf | Vbuf.
template <int MODE>
__global__ __launch_bounds__(256) void gemm_bt(const bf16_t* __restrict__ A,
                                               const bf16_t* __restrict__ Bt,
                                               void* __restrict__ C0v,
                                               void* __restrict__ C1v,
                                               void* __restrict__ C2v,
                                               const float* __restrict__ fr,
                                               int M, int N, int K, int ldc) {
  __shared__ bf16_t As[128 * 64];
  __shared__ bf16_t Bs[128 * 64];
  const int t = threadIdx.x;
  const int w = t >> 6, l = t & 63, l15 = l & 15, lhi = l >> 4;
  const int m0 = blockIdx.y * 128, n0 = blockIdx.x * 128;
  const int wr = (w >> 1) * 64, wc = (w & 1) * 64;

  f32x4 zero = {0.f, 0.f, 0.f, 0.f};
  f32x4 acc[4][4];
#pragma unroll
  for (int m = 0; m < 4; ++m)
#pragma unroll
    for (int n = 0; n < 4; ++n) acc[m][n] = zero;

  const int srow = t >> 3;
  const int scol = (((t & 7) ^ (srow & 7)) << 3);
  const int ldst = t * 8;

  for (int k0 = 0; k0 < K; k0 += 64) {
#pragma unroll
    for (int j = 0; j < 4; ++j) {
      gload16(A + (size_t)(m0 + srow + j * 32) * K + k0 + scol, &As[ldst + j * 2048]);
      gload16(Bt + (size_t)(n0 + srow + j * 32) * K + k0 + scol, &Bs[ldst + j * 2048]);
    }
    __syncthreads();
#pragma unroll
    for (int kk = 0; kk < 2; ++kk) {
      const int xs = ((((kk << 2) + lhi) ^ (l15 & 7)) << 3);
      bf16x8 af[4], bfr[4];
#pragma unroll
      for (int m = 0; m < 4; ++m)
        af[m] = *(const bf16x8*)&As[(wr + m * 16 + l15) * 64 + xs];
#pragma unroll
      for (int n = 0; n < 4; ++n)
        bfr[n] = *(const bf16x8*)&Bs[(wc + n * 16 + l15) * 64 + xs];
#pragma unroll
      for (int m = 0; m < 4; ++m)
#pragma unroll
        for (int n = 0; n < 4; ++n)
          acc[m][n] = __builtin_amdgcn_mfma_f32_16x16x32_bf16(af[m], bfr[n], acc[m][n], 0, 0, 0);
    }
    __syncthreads();
  }

#pragma unroll
  for (int m = 0; m < 4; ++m) {
#pragma unroll
    for (int n = 0; n < 4; ++n) {
#pragma unroll
      for (int r = 0; r < 4; ++r) {
        int row = m0 + wr + m * 16 + lhi * 4 + r;
        int col = n0 + wc + n * 16 + l15;
        float v = acc[m][n][r];
        if (MODE == 1) {
          ((float*)C0v)[(size_t)row * ldc + col] = v;
        } else if (MODE == 3) {
          if (col < 512) {
            ((bf16_t*)C0v)[(size_t)row * 512 + col] = (bf16_t)v;
          } else if (col < 1024) {
            ((bf16_t*)C1v)[(size_t)row * 512 + (col - 512)] = (bf16_t)v;
          } else if (col < 1088) {
            float other = __shfl_xor(v, 1, 64);
            int tt = row & (T_ - 1);
            int j = (col - 1024) >> 1;
            float2 cs = ((const float2*)fr)[tt * 32 + j];
            float o = (col & 1) ? (other * cs.y + v * cs.x) : (v * cs.x - other * cs.y);
            float o2 = __shfl_xor(o, 1, 64);
            if (!(col & 1)) {
              union { bf16_t h2[2]; unsigned u; } pk;
              pk.h2[0] = (bf16_t)o;
              pk.h2[1] = (bf16_t)o2;
              bf16_t* Kb = (bf16_t*)C2v;
#pragma unroll
              for (int hh = 0; hh < H_; ++hh)
                *(unsigned*)&Kb[(size_t)row * QSTRIDE_ + hh * DQK_ + 128 + (col - 1024)] = pk.u;
            }
          }
        } else if (MODE == 4) {
          if (col < 2048) {
            ((bf16_t*)C0v)[(size_t)row * QSTRIDE_ + (col >> 7) * DQK_ + (col & 127)] =
                (bf16_t)(v * SCALE_);
          } else {
            float other = __shfl_xor(v, 1, 64);
            int tt = row & (T_ - 1);
            int j = (col & 63) >> 1;
            float2 cs = ((const float2*)fr)[tt * 32 + j];
            float o = (col & 1) ? (other * cs.y + v * cs.x) : (v * cs.x - other * cs.y);
            int hh = (col - 2048) >> 6;
            ((bf16_t*)C0v)[(size_t)row * QSTRIDE_ + hh * DQK_ + 128 + (col & 63)] =
                (bf16_t)(o * SCALE_);
          }
        } else if (MODE == 5) {
          if (col < 2048) ((bf16_t*)C0v)[(size_t)row * QSTRIDE_ + (col >> 7) * DQK_ + (col & 127)] = (bf16_t)v;
          else            ((bf16_t*)C1v)[(size_t)row * 2048 + (col - 2048)] = (bf16_t)v;
        }
      }
    }
  }
}

// ---------------- causal flash attention v3 + T13 defer-max + deferred l-reduce (R13, 103 us) ----------------
// 512 blocks x 256 threads. Block handles q-tile pair {qp, 31-qp} SEQUENTIALLY:
// every block = exactly 33 equal steps -> sustained 2 blocks/CU. id&7 -> XCD, 4 bh/XCD.
#define KLDB 200
#define VLDB 72
#define PLDB 68

__global__ __launch_bounds__(256, 2) void flash_attn3(const bf16_t* __restrict__ Q,
                                                      const bf16_t* __restrict__ Kb,
                                                      const bf16_t* __restrict__ Vt,
                                                      bf16_t* __restrict__ Ob) {
  __shared__ bf16_t Ks[64 * KLDB];
  __shared__ bf16_t Vs[128 * VLDB];
  __shared__ bf16_t Ps[4][16 * PLDB];

  const int t = threadIdx.x, w = t >> 6, l = t & 63, l15 = l & 15, lhi = l >> 4;
  const int id = blockIdx.x;
  const int xcd = id & 7, sub = id >> 3;
  const int bh = xcd * 4 + (sub >> 4);
  const int qp = sub & 15;
  const int b = bh >> 4, h = bh & 15;
  const int qa = qp, qb = 31 - qp;  // qa < qb always

  int rK[6], cK[6];
#pragma unroll
  for (int i = 0; i < 6; ++i) { int idx = i * 256 + t; rK[i] = idx / 24; cK[i] = idx % 24; }
  const int rVt = t >> 3, cV = t & 7;
  const bf16_t* kbase = Kb + (size_t)b * T_ * QSTRIDE_ + h * DQK_;
  const bf16_t* vbase = Vt + (size_t)bh * DH_ * T_;

  bf16x8 kreg[6], vreg[4];
#define LOAD_TILE(K0)                                                                      \
  do {                                                                                     \
    _Pragma("unroll") for (int i = 0; i < 6; ++i)                                          \
        kreg[i] = *(const bf16x8*)(kbase + (size_t)((K0) + rK[i]) * QSTRIDE_ + cK[i] * 8); \
    _Pragma("unroll") for (int i = 0; i < 4; ++i)                                          \
        vreg[i] = *(const bf16x8*)(vbase + (size_t)(i * 32 + rVt) * T_ + (K0) + cV * 8);   \
  } while (0)
#define WRITE_TILE()                                                                       \
  do {                                                                                     \
    _Pragma("unroll") for (int i = 0; i < 6; ++i)                                          \
        *(bf16x8*)&Ks[rK[i] * KLDB + cK[i] * 8] = kreg[i];                                 \
    _Pragma("unroll") for (int i = 0; i < 4; ++i)                                          \
        *(bf16x8*)&Vs[(i * 32 + rVt) * VLDB + cV * 8] = vreg[i];                           \
  } while (0)

  f32x4 zero = {0.f, 0.f, 0.f, 0.f};

  LOAD_TILE(0);
  WRITE_TILE();
  __syncthreads();

  for (int pass = 0; pass < 2; ++pass) {
    const int qt = pass ? qb : qa;

    bf16x8 qf[6];
    {
      const bf16_t* qrow = Q + ((size_t)(b * T_ + qt * 64 + w * 16 + l15)) * QSTRIDE_ + h * DQK_;
#pragma unroll
      for (int kc = 0; kc < 6; ++kc) qf[kc] = *(const bf16x8*)(qrow + kc * 32 + lhi * 8);
    }

    float m_r[4], l_r[4];  // l_r: PER-LANE partial row sum (reduced once in epilogue)
    f32x4 accO[8];
#pragma unroll
    for (int r = 0; r < 4; ++r) { m_r[r] = -1e30f; l_r[r] = 0.f; }
#pragma unroll
    for (int n = 0; n < 8; ++n) accO[n] = zero;

    for (int kt = 0; kt <= qt; ++kt) {
      const bool last = (kt == qt);
      const bool haveNext = !(pass == 1 && last);
      if (haveNext) LOAD_TILE(last ? 0 : (kt + 1) * 64);  // prefetch (tile 0 for next pass)

      f32x4 s[4];
#pragma unroll
      for (int n = 0; n < 4; ++n) s[n] = zero;
      __builtin_amdgcn_s_setprio(1);
#pragma unroll
      for (int kc = 0; kc < 6; ++kc) {
#pragma unroll
        for (int n = 0; n < 4; ++n) {
          bf16x8 kf = *(const bf16x8*)&Ks[(n * 16 + l15) * KLDB + kc * 32 + lhi * 8];
          s[n] = __builtin_amdgcn_mfma_f32_16x16x32_bf16(qf[kc], kf, s[n], 0, 0, 0);
        }
      }
      __builtin_amdgcn_s_setprio(0);

      // mask (Q pre-scaled; scores already scaled)
      if (last) {
#pragma unroll
        for (int n = 0; n < 4; ++n)
#pragma unroll
          for (int r = 0; r < 4; ++r) {
            int qq = w * 16 + lhi * 4 + r;
            int kk = n * 16 + l15;
            if (kk > qq) s[n][r] = -1e30f;
          }
      }
      // row max of this tile
      float pmax[4];
#pragma unroll
      for (int r = 0; r < 4; ++r) {
        float v = fmaxf(fmaxf(s[0][r], s[1][r]), fmaxf(s[2][r], s[3][r]));
#pragma unroll
        for (int off = 1; off < 16; off <<= 1) v = fmaxf(v, __shfl_xor(v, off, 64));
        pmax[r] = v;
      }
      // T13 defer-max: skip rescale unless any row grew past m_r + 8
      bool need = (pmax[0] > m_r[0] + 8.0f) || (pmax[1] > m_r[1] + 8.0f) ||
                  (pmax[2] > m_r[2] + 8.0f) || (pmax[3] > m_r[3] + 8.0f);
      if (__any(need ? 1 : 0)) {
        float corr[4];
#pragma unroll
        for (int r = 0; r < 4; ++r) {
          float mn = fmaxf(m_r[r], pmax[r]);
          corr[r] = __expf(m_r[r] - mn);   // uniform across the 16-lane row group
          m_r[r] = mn;
          l_r[r] *= corr[r];
        }
#pragma unroll
        for (int n = 0; n < 8; ++n)
#pragma unroll
          for (int r = 0; r < 4; ++r) accO[n][r] *= corr[r];
      }
#pragma unroll
      for (int n = 0; n < 4; ++n)
#pragma unroll
        for (int r = 0; r < 4; ++r) {
          float p = __expf(s[n][r] - m_r[r]);
          l_r[r] += p;  // per-lane partial; no per-kt shfl reduce
          Ps[w][(lhi * 4 + r) * PLDB + n * 16 + l15] = (bf16_t)p;
        }

      __builtin_amdgcn_s_setprio(1);
#pragma unroll
      for (int kc = 0; kc < 2; ++kc) {
        bf16x4 p0 = *(const bf16x4*)&Ps[w][l15 * PLDB + kc * 32 + lhi * 8];
        bf16x4 p1 = *(const bf16x4*)&Ps[w][l15 * PLDB + kc * 32 + lhi * 8 + 4];
        bf16x8 pf = __builtin_shufflevector(p0, p1, 0, 1, 2, 3, 4, 5, 6, 7);
#pragma unroll
        for (int n = 0; n < 8; ++n) {
          bf16x8 vf = *(const bf16x8*)&Vs[(n * 16 + l15) * VLDB + kc * 32 + lhi * 8];
          accO[n] = __builtin_amdgcn_mfma_f32_16x16x32_bf16(pf, vf, accO[n], 0, 0, 0);
        }
      }
      __builtin_amdgcn_s_setprio(0);

      __syncthreads();
      if (haveNext) WRITE_TILE();
      __syncthreads();
    }

    {
      float inv[4];
#pragma unroll
      for (int r = 0; r < 4; ++r) {
        float v = l_r[r];
#pragma unroll
        for (int off = 1; off < 16; off <<= 1) v += __shfl_xor(v, off, 64);
        inv[r] = 1.0f / v;
      }
#pragma unroll
      for (int n = 0; n < 8; ++n)
#pragma unroll
        for (int r = 0; r < 4; ++r) {
          size_t row = (size_t)(b * T_ + qt * 64 + w * 16 + lhi * 4 + r);
          Ob[row * (H_ * DH_) + h * DH_ + n * 16 + l15] = (bf16_t)(accO[n][r] * inv[r]);
        }
    }
  }
#undef LOAD_TILE
#undef WRITE_TILE
}

// ---------------- host ----------------
extern "C" void kernel_launch(void* const* d_in, const int* in_sizes, int n_in,
                              void* d_out, int out_size, void* d_ws, size_t ws_size,
                              hipStream_t stream) {
  (void)in_sizes; (void)n_in; (void)out_size; (void)ws_size;
  const float* x    = (const float*)d_in[0];
  const float* fr   = (const float*)d_in[1];
  // d_in[2] = mask (unused; causal handled analytically)
  const float* Wdq  = (const float*)d_in[3];
  const float* Wuq  = (const float*)d_in[4];
  const float* Wdkv = (const float*)d_in[5];
  const float* Wuk  = (const float*)d_in[6];
  const float* Wuv  = (const float*)d_in[7];
  const float* Wqr  = (const float*)d_in[8];
  const float* Wkr  = (const float*)d_in[9];
  const float* Wo   = (const float*)d_in[10];
  float* out = (float*)d_out;

  char* ws = (char*)d_ws;
  size_t off = 0;
  auto alloc = [&](size_t bytes) -> void* {
    void* p = ws + off;
    off += (bytes + 255) & ~(size_t)255;
    return p;
  };
  bf16_t* x_bf   = (bf16_t*)alloc((size_t)BT_ * DIM_ * 2);
  bf16_t* Bt1    = (bf16_t*)alloc((size_t)1152 * 2048 * 2);  // [Wdq(512) | Wdkv(512) | Wkr(128 pad)]
  bf16_t* Bt2    = (bf16_t*)alloc((size_t)3072 * 512 * 2);   // [Wuq(2048) | Wqr(1024)]
  bf16_t* Bt3    = (bf16_t*)alloc((size_t)4096 * 512 * 2);   // [Wuk(2048) | Wuv(2048)]
  bf16_t* Wo_t   = (bf16_t*)alloc((size_t)2048 * 2048 * 2);
  bf16_t* q_c    = (bf16_t*)alloc((size_t)BT_ * 512 * 2);
  bf16_t* kv_c   = (bf16_t*)alloc((size_t)BT_ * 512 * 2);
  bf16_t* Qbuf   = (bf16_t*)alloc((size_t)BT_ * QSTRIDE_ * 2);
  bf16_t* Kbuf   = (bf16_t*)alloc((size_t)BT_ * QSTRIDE_ * 2);
  bf16_t* Vbuf   = (bf16_t*)alloc((size_t)BT_ * 2048 * 2);
  bf16_t* Vt_g   = (bf16_t*)alloc((size_t)BT_ * 2048 * 2);
  bf16_t* AObuf  = (bf16_t*)alloc((size_t)BT_ * 2048 * 2);

  // 1) prep: weight transposes (9984 blocks) + x cast (8192 blocks), one dispatch
  prep<<<18176, dim3(32, 8), 0, stream>>>(x, Wdq, Wdkv, Wkr, Wuq, Wqr, Wuk, Wuv, Wo,
                                          x_bf, Bt1, Bt2, Bt3, Wo_t);

  // 2-4) fused projections (MODE3 fuses rope-k broadcast; MODE4 fuses RoPE-q + Q pre-scale)
  gemm_bt<3><<<dim3(9, 32),  256, 0, stream>>>(x_bf, Bt1, q_c, kv_c, Kbuf, fr, BT_, 1088, 2048, 0);
  gemm_bt<4><<<dim3(24, 32), 256, 0, stream>>>(q_c,  Bt2, Qbuf, nullptr, nullptr, fr, BT_, 3072, 512, 0);
  gemm_bt<5><<<dim3(32, 32), 256, 0, stream>>>(kv_c, Bt3, Kbuf, Vbuf, nullptr, nullptr, BT_, 4096, 512, 0);

  // 5) V transpose
  transpose_v<<<2048, 256, 0, stream>>>(Vbuf, Vt_g);

  // 6) flash attention (proven v3 shell)
  flash_attn3<<<512, 256, 0, stream>>>(Qbuf, Kbuf, Vt_g, AObuf);

  // 7) output projection -> fp32
  gemm_bt<1><<<dim3(16, 32), 256, 0, stream>>>(AObuf, Wo_t, out, nullptr, nullptr, nullptr, BT_, 2048, 2048, 2048);
}